// Round 2
// baseline (99.670 us; speedup 1.0000x reference)
//
#include <hip/hip_runtime.h>
#include <hip/hip_bf16.h>

typedef __attribute__((ext_vector_type(8))) short short8;
typedef __attribute__((ext_vector_type(4))) float f32x4;

#define PATH_W 0.0625f
#define INV_SQRT3 0.57735026918962576f

__device__ __forceinline__ unsigned short f2bf(float f) {
    unsigned int u = __builtin_bit_cast(unsigned int, f);
    u += 0x7FFFu + ((u >> 16) & 1u);   // round-to-nearest-even
    return (unsigned short)(u >> 16);
}

__device__ __forceinline__ float silu(float x) {
    return x / (1.0f + __expf(-x));
}

// ---------------------------------------------------------------------------
// Prep: block 0 computes the 5 per-channel coefficient vectors with the
// constant factors FOLDED IN:
//   aq = PATH_W * (wq_s @ Wq0), bq = PATH_W * (wq_s @ bq)
//   av = PATH_W * (wv_s @ Wv0), bv = PATH_W * (wv_s @ bv)
//   a1 = PATH_W * INV_SQRT3 * (wv_v @ Wv1)
// Blocks 1..128 pack W1/W2/W3 into frag-major bf16 A-fragments (unchanged).
// ---------------------------------------------------------------------------
__global__ void prep_all(const float* __restrict__ Wq0, const float* __restrict__ bq,
                         const float* __restrict__ Wv0, const float* __restrict__ bv,
                         const float* __restrict__ Wv1, const float* __restrict__ wq_s,
                         const float* __restrict__ wv_s, const float* __restrict__ wv_v,
                         const float* __restrict__ W1, const float* __restrict__ W2,
                         const float* __restrict__ W3,
                         float* __restrict__ vecs, unsigned short* __restrict__ wp) {
    if (blockIdx.x == 0) {
        int u = threadIdx.x;  // 0..127
        float aq = 0.f, bqs = 0.f, av = 0.f, bvs = 0.f, a1 = 0.f;
        for (int v = 0; v < 128; ++v) {
            float rq = wq_s[u * 128 + v];
            float rv = wv_s[u * 128 + v];
            aq  += Wq0[v] * rq;
            bqs += bq[v]  * rq;
            av  += Wv0[v] * rv;
            bvs += bv[v]  * rv;
            a1  += Wv1[v] * wv_v[u * 128 + v];
        }
        vecs[u]       = PATH_W * aq;
        vecs[128 + u] = PATH_W * bqs;
        vecs[256 + u] = PATH_W * av;
        vecs[384 + u] = PATH_W * bvs;
        vecs[512 + u] = PATH_W * INV_SQRT3 * a1;
        return;
    }
    int fid  = blockIdx.x - 1;      // 0..127
    int t    = threadIdx.x;         // 0..127
    int lane = t & 63;
    int half = t >> 6;
    int g  = lane >> 4;
    int r  = lane & 15;
    const float* W;
    int mt, ks;
    if (fid < 64)      { W = W1; mt = fid >> 3;        ks = fid & 7; }
    else if (fid < 96) { W = W2; mt = (fid - 64) >> 2; ks = (fid - 64) & 3; }
    else               { W = W3; mt = (fid - 96) >> 2; ks = (fid - 96) & 3; }
    int col  = mt * 16 + r;
    int row0 = ks * 32 + g * 8 + half * 4;
    unsigned short* dst = wp + fid * 512 + lane * 8 + half * 4;
    #pragma unroll
    for (int j = 0; j < 4; ++j) dst[j] = f2bf(W[(row0 + j) * 128 + col]);
}

// ---------------------------------------------------------------------------
// Fused main kernel: 8 waves x 16 nodes = 128 nodes/block.
// Front-end: coalesced k-quarter staging of node rows into per-wave 8KB LDS
// (XOR-swizzled chunks), software-pipelined, then per-lane gather from LDS.
// Back-end (GEMM1..3, transposes, epilogue): unchanged from passing version.
// ---------------------------------------------------------------------------
__global__ __launch_bounds__(512, 4) void fused_main(
    const float* __restrict__ nf,     // node_feats [N,512]
    const float* __restrict__ field,  // field_feats [N,4]
    const float* __restrict__ c0, const float* __restrict__ ci,
    const float* __restrict__ vecs,   // 5 x 128 f32 (pre-scaled)
    const unsigned short* __restrict__ wp,  // packed bf16 frags
    const float* __restrict__ W4, const float* __restrict__ b1,
    const float* __restrict__ b2, const float* __restrict__ b3,
    const float* __restrict__ b4, float* __restrict__ out, int N)
{
    __shared__ __align__(16) char smem[65536];
    __shared__ __align__(16) float vlds[640];
    const int tid  = threadIdx.x;
    const int wave = tid >> 6;
    const int lane = tid & 63;
    const int g    = lane >> 4;     // k-group within frag
    const int nl   = lane & 15;     // node-in-wave == MFMA column
    const int nodebase = blockIdx.x * 128 + wave * 16;
    const int nd   = nodebase + nl;
    const int ndc  = nd < N ? nd : N - 1;

    char* sbuf = smem + wave * 8192;   // per-wave staging buffer (16 nodes x 512B)

    // stage coefficient vectors into LDS (640 f32 = 160 f32x4)
    if (tid < 160)
        reinterpret_cast<f32x4*>(vlds)[tid] = reinterpret_cast<const f32x4*>(vecs)[tid];

    // staging lane roles: instr i covers nodes {2i, 2i+1}; 32 chunks (16B) per node:
    //   chunk c<8  -> s   floats [32k+4c, +4)
    //   chunk c>=8 -> vec floats [128+96k+4(c-8), +4)
    const int c   = lane & 31;
    const int nlo = lane >> 5;   // node parity within instr

    f32x4 buf[8];
    // issue phase-0 global loads (coalesced: 2 nodes x (128B s-run + 384B v-run))
    #pragma unroll
    for (int i = 0; i < 8; ++i) {
        int ng = nodebase + 2 * i + nlo;
        ng = ng < N ? ng : N - 1;
        int fo = (c < 8) ? (4 * c) : (128 + 4 * (c - 8));
        buf[i] = *reinterpret_cast<const f32x4*>(nf + ng * 512 + fo);
    }

    const float q_in = c0[ndc] + ci[ndc];
    const f32x4 ff   = reinterpret_cast<const f32x4*>(field)[ndc];

    __syncthreads();   // vlds visible to all waves

    const f32x4* vl4 = reinterpret_cast<const f32x4*>(vlds);
    short8 hfrag[8];

    #pragma unroll
    for (int k = 0; k < 4; ++k) {
        // write stage k into per-wave LDS (chunk-XOR swizzle by node)
        #pragma unroll
        for (int i = 0; i < 8; ++i) {
            int nloc = 2 * i + nlo;
            *reinterpret_cast<f32x4*>(sbuf + nloc * 512 + ((c ^ (nloc & 7)) * 16)) = buf[i];
        }
        // prefetch phase k+1 (overlaps with compute below)
        if (k < 3) {
            #pragma unroll
            for (int i = 0; i < 8; ++i) {
                int ng = nodebase + 2 * i + nlo;
                ng = ng < N ? ng : N - 1;
                int fo = (c < 8) ? (32 * (k + 1) + 4 * c)
                                 : (128 + 96 * (k + 1) + 4 * (c - 8));
                buf[i] = *reinterpret_cast<const f32x4*>(nf + ng * 512 + fo);
            }
        }
        asm volatile("s_waitcnt lgkmcnt(0)" ::: "memory");
        // gather + compute h channels [32k, 32k+32) for this lane's node
        #pragma unroll
        for (int h = 0; h < 2; ++h) {
            const int cs = 2 * g + h;
            const int m  = 8 * k + cs;     // global channel-block index
            const int sw = nl & 7;
            f32x4 s  = *reinterpret_cast<const f32x4*>(sbuf + nl * 512 + ((cs)          ^ sw) * 16);
            f32x4 va = *reinterpret_cast<const f32x4*>(sbuf + nl * 512 + ((8 + 3 * cs)  ^ sw) * 16);
            f32x4 vb = *reinterpret_cast<const f32x4*>(sbuf + nl * 512 + ((9 + 3 * cs)  ^ sw) * 16);
            f32x4 vc = *reinterpret_cast<const f32x4*>(sbuf + nl * 512 + ((10 + 3 * cs) ^ sw) * 16);
            f32x4 aq = vl4[m], bqv = vl4[32 + m], av = vl4[64 + m],
                  bvv = vl4[96 + m], a1 = vl4[128 + m];
            float vx[4], vy[4], vz[4];
            vx[0] = va[0]; vy[0] = va[1]; vz[0] = va[2];
            vx[1] = va[3]; vy[1] = vb[0]; vz[1] = vb[1];
            vx[2] = vb[2]; vy[2] = vb[3]; vz[2] = vc[0];
            vx[3] = vc[1]; vy[3] = vc[2]; vz[3] = vc[3];
            #pragma unroll
            for (int j = 0; j < 4; ++j) {
                float sc = s[j];
                float hq = sc * fmaf(q_in, aq[j], bqv[j]);
                float d3 = fmaf(vx[j], ff[1], fmaf(vy[j], ff[2], vz[j] * ff[3]));
                float hv = fmaf(sc, fmaf(ff[0], av[j], bvv[j]), a1[j] * d3);
                hfrag[k][4 * h + j]     = (short)f2bf(hq);
                hfrag[k + 4][4 * h + j] = (short)f2bf(hv);
            }
        }
    }
    __syncthreads();   // all waves done with staging buffers; overlay W1

    // ---- stage W1 frags (64KB) into LDS (linear copy, coalesced) ----
    {
        const f32x4* src = reinterpret_cast<const f32x4*>(wp);
        f32x4* dst = reinterpret_cast<f32x4*>(smem);
        #pragma unroll
        for (int i = 0; i < 8; ++i) dst[tid + i * 512] = src[tid + i * 512];
    }
    __syncthreads();   // W1 staged

    // ---- GEMM1: h1_pre[f][n] = b1 + sum_u W1[u][f] h[n][u]  (K=256) ----
    f32x4 acc[8];
    #pragma unroll
    for (int mt = 0; mt < 8; ++mt)
        acc[mt] = reinterpret_cast<const f32x4*>(b1)[mt * 4 + g];
    #pragma unroll
    for (int ks = 0; ks < 8; ++ks) {
        #pragma unroll
        for (int mt = 0; mt < 8; ++mt) {
            short8 a = *reinterpret_cast<const short8*>(
                smem + (mt * 8 + ks) * 1024 + lane * 16);
            acc[mt] = __builtin_amdgcn_mfma_f32_16x16x32_bf16(a, hfrag[ks], acc[mt], 0, 0, 0);
        }
    }
    __syncthreads();   // all waves done reading W1; its LDS is now free

    // ---- silu + transpose h1 into per-wave buffer (XOR-swizzled) ----
    char* tbuf = smem + wave * 4096;   // 16 nodes x 128 feats bf16
    #pragma unroll
    for (int mt = 0; mt < 8; ++mt) {
        float x0 = silu(acc[mt][0]), x1 = silu(acc[mt][1]);
        float x2 = silu(acc[mt][2]), x3 = silu(acc[mt][3]);
        unsigned int w0 = (unsigned int)f2bf(x0) | ((unsigned int)f2bf(x1) << 16);
        unsigned int w1 = (unsigned int)f2bf(x2) | ((unsigned int)f2bf(x3) << 16);
        int fs = (mt * 16 + g * 4) ^ (nl << 3);   // swizzle feat bits 3..6 by node
        *reinterpret_cast<unsigned int*>(tbuf + nl * 256 + fs * 2)     = w0;
        *reinterpret_cast<unsigned int*>(tbuf + nl * 256 + fs * 2 + 4) = w1;
    }
    __syncthreads();
    short8 h1frag[4];
    #pragma unroll
    for (int ks = 0; ks < 4; ++ks) {
        int F = (ks * 32 + g * 8) ^ (nl << 3);
        h1frag[ks] = *reinterpret_cast<const short8*>(tbuf + nl * 256 + F * 2);
    }
    __syncthreads();   // done reading transpose region

    // ---- stage W2 (32KB) + W3 (32KB) into LDS ----
    {
        const f32x4* src = reinterpret_cast<const f32x4*>(wp + 64 * 512);
        f32x4* dst = reinterpret_cast<f32x4*>(smem);
        #pragma unroll
        for (int i = 0; i < 8; ++i) dst[tid + i * 512] = src[tid + i * 512];
    }
    __syncthreads();

    // ---- GEMM2 (K=128) ----
    f32x4 acc2[8];
    #pragma unroll
    for (int mt = 0; mt < 8; ++mt)
        acc2[mt] = reinterpret_cast<const f32x4*>(b2)[mt * 4 + g];
    #pragma unroll
    for (int ks = 0; ks < 4; ++ks) {
        #pragma unroll
        for (int mt = 0; mt < 8; ++mt) {
            short8 a = *reinterpret_cast<const short8*>(
                smem + (mt * 4 + ks) * 1024 + lane * 16);
            acc2[mt] = __builtin_amdgcn_mfma_f32_16x16x32_bf16(a, h1frag[ks], acc2[mt], 0, 0, 0);
        }
    }
    __syncthreads();   // all waves done reading W2; overlay transpose there

    // ---- silu + transpose h2 ----
    #pragma unroll
    for (int mt = 0; mt < 8; ++mt) {
        float x0 = silu(acc2[mt][0]), x1 = silu(acc2[mt][1]);
        float x2 = silu(acc2[mt][2]), x3 = silu(acc2[mt][3]);
        unsigned int w0 = (unsigned int)f2bf(x0) | ((unsigned int)f2bf(x1) << 16);
        unsigned int w1 = (unsigned int)f2bf(x2) | ((unsigned int)f2bf(x3) << 16);
        int fs = (mt * 16 + g * 4) ^ (nl << 3);
        *reinterpret_cast<unsigned int*>(tbuf + nl * 256 + fs * 2)     = w0;
        *reinterpret_cast<unsigned int*>(tbuf + nl * 256 + fs * 2 + 4) = w1;
    }
    __syncthreads();
    short8 h2frag[4];
    #pragma unroll
    for (int ks = 0; ks < 4; ++ks) {
        int F = (ks * 32 + g * 8) ^ (nl << 3);
        h2frag[ks] = *reinterpret_cast<const short8*>(tbuf + nl * 256 + F * 2);
    }
    // W3 region [32K,64K) untouched by transposes -> no barrier needed here

    // ---- GEMM3 (K=128) ----
    f32x4 acc3[8];
    #pragma unroll
    for (int mt = 0; mt < 8; ++mt)
        acc3[mt] = reinterpret_cast<const f32x4*>(b3)[mt * 4 + g];
    #pragma unroll
    for (int ks = 0; ks < 4; ++ks) {
        #pragma unroll
        for (int mt = 0; mt < 8; ++mt) {
            short8 a = *reinterpret_cast<const short8*>(
                smem + 32768 + (mt * 4 + ks) * 1024 + lane * 16);
            acc3[mt] = __builtin_amdgcn_mfma_f32_16x16x32_bf16(a, h2frag[ks], acc3[mt], 0, 0, 0);
        }
    }

    // ---- epilogue: out[n] = silu(h3) . W4 + b4 (reduce over g-groups) ----
    float acc_out = 0.f;
    #pragma unroll
    for (int mt = 0; mt < 8; ++mt) {
        f32x4 w4v = reinterpret_cast<const f32x4*>(W4)[mt * 4 + g];
        acc_out += silu(acc3[mt][0]) * w4v[0];
        acc_out += silu(acc3[mt][1]) * w4v[1];
        acc_out += silu(acc3[mt][2]) * w4v[2];
        acc_out += silu(acc3[mt][3]) * w4v[3];
    }
    acc_out += __shfl_xor(acc_out, 16, 64);
    acc_out += __shfl_xor(acc_out, 32, 64);
    if (g == 0 && nd < N) out[nd] = acc_out + b4[0];
}

extern "C" void kernel_launch(void* const* d_in, const int* in_sizes, int n_in,
                              void* d_out, int out_size, void* d_ws, size_t ws_size,
                              hipStream_t stream) {
    const float* node_feats = (const float*)d_in[1];
    const float* field      = (const float*)d_in[5];
    const float* c0         = (const float*)d_in[6];
    const float* ci         = (const float*)d_in[7];
    const float* Wq0        = (const float*)d_in[8];
    const float* bq         = (const float*)d_in[9];
    const float* Wv0        = (const float*)d_in[10];
    const float* bv         = (const float*)d_in[11];
    const float* Wv1        = (const float*)d_in[12];
    const float* wq_s       = (const float*)d_in[13];
    // d_in[14] = wq_v is multiplied by q_up_v == 0 in the reference -> unused
    const float* wv_s       = (const float*)d_in[15];
    const float* wv_v       = (const float*)d_in[16];
    const float* W1         = (const float*)d_in[17];
    const float* b1         = (const float*)d_in[18];
    const float* W2         = (const float*)d_in[19];
    const float* b2         = (const float*)d_in[20];
    const float* W3         = (const float*)d_in[21];
    const float* b3         = (const float*)d_in[22];
    const float* W4         = (const float*)d_in[23];
    const float* b4         = (const float*)d_in[24];

    const int N = in_sizes[1] / 512;           // node_feats is [N, 4*C]
    float* vecs = (float*)d_ws;                 // 640 f32
    unsigned short* wp = (unsigned short*)((char*)d_ws + 4096);  // 128 frags x 1KB

    prep_all<<<129, 128, 0, stream>>>(Wq0, bq, Wv0, bv, Wv1, wq_s, wv_s, wv_v,
                                      W1, W2, W3, vecs, wp);
    const int blocks = (N + 127) / 128;
    fused_main<<<blocks, 512, 0, stream>>>(node_feats, field, c0, ci, vecs, wp,
                                           W4, b1, b2, b3, b4, (float*)d_out, N);
}

// Round 3
// 78.783 us; speedup vs baseline: 1.2651x; 1.2651x over previous
//
#include <hip/hip_runtime.h>
#include <hip/hip_bf16.h>

typedef __attribute__((ext_vector_type(8))) short short8;
typedef __attribute__((ext_vector_type(4))) float f32x4;

#define PATH_W 0.0625f
#define INV_SQRT3 0.57735026918962576f

typedef const __attribute__((address_space(1))) char gchar;
typedef __attribute__((address_space(3))) char schar;

__device__ __forceinline__ unsigned short f2bf(float f) {
    unsigned int u = __builtin_bit_cast(unsigned int, f);
    u += 0x7FFFu + ((u >> 16) & 1u);   // round-to-nearest-even
    return (unsigned short)(u >> 16);
}

__device__ __forceinline__ float silu(float x) {
    return x / (1.0f + __expf(-x));
}

// ---------------------------------------------------------------------------
// Prep: block 0 computes the 5 per-channel coefficient vectors (constants
// folded in). Blocks 1..128 pack W1/W2/W3 into frag-major bf16 A-fragments.
//  W1 (fid 0..63, fid=mt*8+ks):  k = ks*32 + g*8 + slot        (slot=half*4+j)
//  W2 (fid 64..95, fid-64=mt*4+ks): k = half*64 + ks*16 + g*4 + j   (phi-pack:
//  matches the GEMM1 D-register layout so NO transpose is needed between GEMMs)
//  W3 (fid 96..127): same phi-pack as W2.
// ---------------------------------------------------------------------------
__global__ void prep_all(const float* __restrict__ Wq0, const float* __restrict__ bq,
                         const float* __restrict__ Wv0, const float* __restrict__ bv,
                         const float* __restrict__ Wv1, const float* __restrict__ wq_s,
                         const float* __restrict__ wv_s, const float* __restrict__ wv_v,
                         const float* __restrict__ W1, const float* __restrict__ W2,
                         const float* __restrict__ W3,
                         float* __restrict__ vecs, unsigned short* __restrict__ wp) {
    if (blockIdx.x == 0) {
        int u = threadIdx.x;  // 0..127
        float aq = 0.f, bqs = 0.f, av = 0.f, bvs = 0.f, a1 = 0.f;
        for (int v = 0; v < 128; ++v) {
            float rq = wq_s[u * 128 + v];
            float rv = wv_s[u * 128 + v];
            aq  += Wq0[v] * rq;
            bqs += bq[v]  * rq;
            av  += Wv0[v] * rv;
            bvs += bv[v]  * rv;
            a1  += Wv1[v] * wv_v[u * 128 + v];
        }
        vecs[u]       = PATH_W * aq;
        vecs[128 + u] = PATH_W * bqs;
        vecs[256 + u] = PATH_W * av;
        vecs[384 + u] = PATH_W * bvs;
        vecs[512 + u] = PATH_W * INV_SQRT3 * a1;
        return;
    }
    int fid  = blockIdx.x - 1;      // 0..127
    int t    = threadIdx.x;         // 0..127
    int lane = t & 63;
    int half = t >> 6;
    int g  = lane >> 4;
    int r  = lane & 15;
    const float* W;
    int row0, col;
    if (fid < 64) {                       // W1: standard pack
        int mt = fid >> 3, ks = fid & 7;
        W = W1; col = mt * 16 + r;
        row0 = ks * 32 + g * 8 + half * 4;
    } else {                              // W2/W3: phi-pack
        int f2 = fid < 96 ? fid - 64 : fid - 96;
        int mt = f2 >> 2, ks = f2 & 3;
        W = fid < 96 ? W2 : W3; col = mt * 16 + r;
        row0 = half * 64 + ks * 16 + g * 4;
    }
    unsigned short* dst = wp + fid * 512 + lane * 8 + half * 4;
    #pragma unroll
    for (int j = 0; j < 4; ++j) dst[j] = f2bf(W[(row0 + j) * 128 + col]);
}

// ---------------------------------------------------------------------------
// Fused main: 8 waves x 16 nodes = 128 nodes/block.
// Phase 1: gl_lds W1 (64KB) + ring-buffered node gather + per-quarter GEMM1.
// Phase 2: gl_lds W2|W3 over W1, GEMM2 -> GEMM3 -> dot-W4 epilogue.
// No inter-GEMM transposes (phi-packed weights). 3 barriers total.
// ---------------------------------------------------------------------------
__global__ __launch_bounds__(512, 4) void fused_main(
    const float* __restrict__ nf,     // node_feats [N,512]
    const float* __restrict__ field,  // field_feats [N,4]
    const float* __restrict__ c0, const float* __restrict__ ci,
    const float* __restrict__ vecs,   // 5 x 128 f32 (pre-scaled)
    const unsigned short* __restrict__ wp,  // packed bf16 frags (128KB)
    const float* __restrict__ W4, const float* __restrict__ b1,
    const float* __restrict__ b2, const float* __restrict__ b3,
    const float* __restrict__ b4, float* __restrict__ out, int N)
{
    __shared__ __align__(16) char smem[65536];
    __shared__ __align__(16) float vlds[640];
    const int tid  = threadIdx.x;
    const int wave = tid >> 6;
    const int lane = tid & 63;
    const int g    = lane >> 4;     // k-group within frag
    const int nl   = lane & 15;     // node-in-wave == MFMA column
    const int nd   = blockIdx.x * 128 + wave * 16 + nl;
    const int ndc  = nd < N ? nd : N - 1;
    const char* wpb = (const char*)wp;

    // ---- async-stage W1 (64KB) straight into LDS, zero VGPRs ----
    #pragma unroll
    for (int i = 0; i < 8; ++i) {
        int off = wave * 8192 + i * 1024;
        __builtin_amdgcn_global_load_lds((gchar*)(wpb + off + lane * 16),
                                         (schar*)(smem + off), 16, 0, 0);
    }

    // ---- coefficient vectors -> LDS (wave 0 only; drained by barrier A) ----
    if (wave == 0) {
        #pragma unroll
        for (int i = 0; i < 3; ++i) {
            int idx = lane + 64 * i;
            if (idx < 160)
                reinterpret_cast<f32x4*>(vlds)[idx] =
                    reinterpret_cast<const f32x4*>(vecs)[idx];
        }
    }

    const float q_in = c0[ndc] + ci[ndc];
    const f32x4 ff   = reinterpret_cast<const f32x4*>(field)[ndc];
    const char* nrow = (const char*)(nf + (size_t)ndc * 512);

    // ring buffers: 3 in-flight half-quarters (s 16B + v 48B each)
    f32x4 hs[3], hv0[3], hv1[3], hv2[3];
#define LOADH(slot, hh) {                                                    \
        const int k_ = (hh) >> 1, h_ = (hh) & 1;                             \
        const char* p_ = nrow + 512 + 384 * k_ + 96 * g + 48 * h_;           \
        hs[slot]  = *reinterpret_cast<const f32x4*>(nrow + 128 * k_ + 32 * g + 16 * h_); \
        hv0[slot] = *reinterpret_cast<const f32x4*>(p_);                     \
        hv1[slot] = *reinterpret_cast<const f32x4*>(p_ + 16);                \
        hv2[slot] = *reinterpret_cast<const f32x4*>(p_ + 32); }

    LOADH(0, 0)
    LOADH(1, 1)

    __syncthreads();   // A: W1 + vlds resident (drains vmcnt/lgkmcnt)

    // ---- GEMM1 interleaved with node gather (K=256, 64 MFMA) ----
    f32x4 acc[8];
    #pragma unroll
    for (int mt = 0; mt < 8; ++mt)
        acc[mt] = reinterpret_cast<const f32x4*>(b1)[mt * 4 + g];

    const f32x4* vl4 = reinterpret_cast<const f32x4*>(vlds);
    short8 hfA, hfB;
    #pragma unroll
    for (int hh = 0; hh < 8; ++hh) {
        const int k = hh >> 1, h = hh & 1, slot = hh % 3;
        if (hh < 6) LOADH((hh + 2) % 3, hh + 2)
        const int m = 8 * k + 2 * g + h;
        f32x4 aq = vl4[m], bqv = vl4[32 + m], av = vl4[64 + m],
              bvv = vl4[96 + m], a1 = vl4[128 + m];
        f32x4 s = hs[slot], va = hv0[slot], vb = hv1[slot], vc = hv2[slot];
        float d3[4];
        d3[0] = fmaf(va[0], ff[1], fmaf(va[1], ff[2], va[2] * ff[3]));
        d3[1] = fmaf(va[3], ff[1], fmaf(vb[0], ff[2], vb[1] * ff[3]));
        d3[2] = fmaf(vb[2], ff[1], fmaf(vb[3], ff[2], vc[0] * ff[3]));
        d3[3] = fmaf(vc[1], ff[1], fmaf(vc[2], ff[2], vc[3] * ff[3]));
        #pragma unroll
        for (int j = 0; j < 4; ++j) {
            float hq = s[j] * fmaf(q_in, aq[j], bqv[j]);
            float hv = fmaf(s[j], fmaf(ff[0], av[j], bvv[j]), a1[j] * d3[j]);
            if (h == 0) { hfA[j]     = (short)f2bf(hq); hfB[j]     = (short)f2bf(hv); }
            else        { hfA[4 + j] = (short)f2bf(hq); hfB[4 + j] = (short)f2bf(hv); }
        }
        if (h == 1) {   // quarter k complete: consume hfA (ks=k), hfB (ks=k+4)
            #pragma unroll
            for (int mt = 0; mt < 8; ++mt) {
                short8 a0 = *reinterpret_cast<const short8*>(
                    smem + (mt * 8 + k) * 1024 + lane * 16);
                acc[mt] = __builtin_amdgcn_mfma_f32_16x16x32_bf16(a0, hfA, acc[mt], 0, 0, 0);
                short8 a4 = *reinterpret_cast<const short8*>(
                    smem + (mt * 8 + k + 4) * 1024 + lane * 16);
                acc[mt] = __builtin_amdgcn_mfma_f32_16x16x32_bf16(a4, hfB, acc[mt], 0, 0, 0);
            }
        }
    }
#undef LOADH

    __syncthreads();   // B: all waves done reading W1

    // ---- async-stage W2 (->[0,32K)) and W3 (->[32K,64K)) over W1 ----
    #pragma unroll
    for (int i = 0; i < 8; ++i) {
        int off = wave * 8192 + i * 1024;
        __builtin_amdgcn_global_load_lds((gchar*)(wpb + 65536 + off + lane * 16),
                                         (schar*)(smem + off), 16, 0, 0);
    }

    // repack GEMM1 output directly into GEMM2 B-fragments (phi convention)
    short8 hf2[4];
    #pragma unroll
    for (int ks = 0; ks < 4; ++ks)
        #pragma unroll
        for (int hp = 0; hp < 2; ++hp)
            #pragma unroll
            for (int j = 0; j < 4; ++j)
                hf2[ks][hp * 4 + j] = (short)f2bf(silu(acc[hp * 4 + ks][j]));

    __syncthreads();   // C: W2/W3 resident

    // ---- GEMM2 (K=128, 32 MFMA) ----
    f32x4 acc2[8];
    #pragma unroll
    for (int mt = 0; mt < 8; ++mt)
        acc2[mt] = reinterpret_cast<const f32x4*>(b2)[mt * 4 + g];
    #pragma unroll
    for (int ks = 0; ks < 4; ++ks) {
        #pragma unroll
        for (int mt = 0; mt < 8; ++mt) {
            short8 a = *reinterpret_cast<const short8*>(
                smem + (mt * 4 + ks) * 1024 + lane * 16);
            acc2[mt] = __builtin_amdgcn_mfma_f32_16x16x32_bf16(a, hf2[ks], acc2[mt], 0, 0, 0);
        }
    }

    // ---- GEMM3 (K=128, 32 MFMA), B-frag = repacked GEMM2 output ----
    short8 hf3[4];
    #pragma unroll
    for (int ks = 0; ks < 4; ++ks)
        #pragma unroll
        for (int hp = 0; hp < 2; ++hp)
            #pragma unroll
            for (int j = 0; j < 4; ++j)
                hf3[ks][hp * 4 + j] = (short)f2bf(silu(acc2[hp * 4 + ks][j]));

    f32x4 acc3[8];
    #pragma unroll
    for (int mt = 0; mt < 8; ++mt)
        acc3[mt] = reinterpret_cast<const f32x4*>(b3)[mt * 4 + g];
    #pragma unroll
    for (int ks = 0; ks < 4; ++ks) {
        #pragma unroll
        for (int mt = 0; mt < 8; ++mt) {
            short8 a = *reinterpret_cast<const short8*>(
                smem + 32768 + (mt * 4 + ks) * 1024 + lane * 16);
            acc3[mt] = __builtin_amdgcn_mfma_f32_16x16x32_bf16(a, hf3[ks], acc3[mt], 0, 0, 0);
        }
    }

    // ---- epilogue: out[n] = silu(h3) . W4 + b4 ----
    float acc_out = 0.f;
    #pragma unroll
    for (int mt = 0; mt < 8; ++mt) {
        f32x4 w4v = reinterpret_cast<const f32x4*>(W4)[mt * 4 + g];
        acc_out += silu(acc3[mt][0]) * w4v[0];
        acc_out += silu(acc3[mt][1]) * w4v[1];
        acc_out += silu(acc3[mt][2]) * w4v[2];
        acc_out += silu(acc3[mt][3]) * w4v[3];
    }
    acc_out += __shfl_xor(acc_out, 16, 64);
    acc_out += __shfl_xor(acc_out, 32, 64);
    if (g == 0 && nd < N) out[nd] = acc_out + b4[0];
}

extern "C" void kernel_launch(void* const* d_in, const int* in_sizes, int n_in,
                              void* d_out, int out_size, void* d_ws, size_t ws_size,
                              hipStream_t stream) {
    const float* node_feats = (const float*)d_in[1];
    const float* field      = (const float*)d_in[5];
    const float* c0         = (const float*)d_in[6];
    const float* ci         = (const float*)d_in[7];
    const float* Wq0        = (const float*)d_in[8];
    const float* bq         = (const float*)d_in[9];
    const float* Wv0        = (const float*)d_in[10];
    const float* bv         = (const float*)d_in[11];
    const float* Wv1        = (const float*)d_in[12];
    const float* wq_s       = (const float*)d_in[13];
    // d_in[14] = wq_v multiplies q_up_v == 0 -> unused
    const float* wv_s       = (const float*)d_in[15];
    const float* wv_v       = (const float*)d_in[16];
    const float* W1         = (const float*)d_in[17];
    const float* b1         = (const float*)d_in[18];
    const float* W2         = (const float*)d_in[19];
    const float* b2         = (const float*)d_in[20];
    const float* W3         = (const float*)d_in[21];
    const float* b3         = (const float*)d_in[22];
    const float* W4         = (const float*)d_in[23];
    const float* b4         = (const float*)d_in[24];

    const int N = in_sizes[1] / 512;           // node_feats is [N, 4*C]
    float* vecs = (float*)d_ws;                 // 640 f32
    unsigned short* wp = (unsigned short*)((char*)d_ws + 4096);  // 128 frags x 1KB

    prep_all<<<129, 128, 0, stream>>>(Wq0, bq, Wv0, bv, Wv1, wq_s, wv_s, wv_v,
                                      W1, W2, W3, vecs, wp);
    const int blocks = (N + 127) / 128;
    fused_main<<<blocks, 512, 0, stream>>>(node_feats, field, c0, ci, vecs, wp,
                                           W4, b1, b2, b3, b4, (float*)d_out, N);
}